// Round 11
// baseline (409.509 us; speedup 1.0000x reference)
//
#include <hip/hip_runtime.h>

// GraphTemporal: N=50000, E=500000, B=64, H=64, L=4 shared layers.
// msg = relu(y[row] + dist*p + q), y = x @ W_el[:, :64].T
// Layer 0: y AND x computed on the fly from v0,v1 (rank-2 closed form).
// 16-NODE TILES, 256 threads -> ~16.5KB LDS -> 8 blocks/CU (occupancy-driven).
// Edges CSR-sorted by destination; aggregation fused into k_node stage 0:
//   dual-edge half-wave (32 lanes/edge, dword=2ch/lane), per-wave contiguous
//   edge quarters, wave-private LDS meta slice + reg prefetch, running-max.
// Per-graph max via disjoint per-tile scratch reduced in k_graph (256 thr).

typedef __attribute__((ext_vector_type(8))) short short8;
typedef __attribute__((ext_vector_type(4))) float f32x4;

__device__ __forceinline__ unsigned short f2bf(float f) {
  union { float f; unsigned u; } v; v.f = f;
  unsigned r = v.u + 0x7FFFu + ((v.u >> 16) & 1u);
  return (unsigned short)(r >> 16);
}
__device__ __forceinline__ float bf2f(unsigned short s) {
  return __uint_as_float((unsigned)s << 16);
}
__device__ __forceinline__ unsigned enc_ordered(float f) {
  unsigned u = __float_as_uint(f);
  return (u >> 31) ? ~u : (u | 0x80000000u);
}

// fused init: graph ranges, u=0, xu_enc, bf16 weights, deg/cur=0, p/q/c0..c2
__global__ void k_init(const float* __restrict__ v0, const float* __restrict__ v1,
                       const float* __restrict__ wte,
                       const float* __restrict__ Wi0, const float* __restrict__ bi0,
                       const float* __restrict__ Wi1, const float* __restrict__ bi1,
                       const int* __restrict__ batch,
                       int* __restrict__ gstart, int* __restrict__ gend,
                       float* __restrict__ u, unsigned* __restrict__ xu_enc,
                       unsigned short* __restrict__ W1b, unsigned short* __restrict__ W2b,
                       unsigned short* __restrict__ Welb,
                       const float* __restrict__ W_n1, const float* __restrict__ W_n2,
                       const float* __restrict__ W_el,
                       const float* __restrict__ b_el,
                       const float* __restrict__ W_edge, const float* __restrict__ b_edge,
                       float* __restrict__ p, float* __restrict__ q,
                       float* __restrict__ c0, float* __restrict__ c1,
                       float* __restrict__ c2,
                       int* __restrict__ deg, int* __restrict__ cur, int N) {
  int i = blockIdx.x * 256 + threadIdx.x;
  if (i < 4096) {
    u[i] = 0.f;
  } else if (i < 8192) {
    xu_enc[i - 4096] = 0x007FFFFFu;  // enc(-inf)
  } else if (i < 8192 + 49152) {
    int j = i - 8192;                 // W_n1 [256][192]
    W1b[j] = f2bf(W_n1[j]);
  } else if (i < 8192 + 49152 + 16384) {
    int j = i - 57344;                // W_n2 [64][256]
    W2b[j] = f2bf(W_n2[j]);
  } else if (i < 77824) {
    int j = i - 73728;                // W_el[:, :64] compact stride 64
    Welb[j] = f2bf(W_el[(j >> 6) * 128 + (j & 63)]);
  } else if (i < 77824 + N) {
    deg[i - 77824] = 0;
  } else if (i < 77824 + 2 * N) {
    cur[i - 77824 - N] = 0;
  } else if (i < 77824 + 3 * N) {
    int n = i - 77824 - 2 * N;        // graph range detection (unique writer)
    int bg = batch[n];
    if (n == 0 || batch[n - 1] != bg) gstart[bg] = n;
    if (n == N - 1 || batch[n + 1] != bg) gend[bg] = n + 1;
  } else if (i < 77824 + 3 * N + 64) {
    int h = i - 77824 - 3 * N;
    float pp = 0.f, qq = 0.f, s0 = 0.f, s1 = 0.f, s2 = 0.f;
    for (int k = 0; k < 64; ++k) {
      float w2 = W_el[h * 128 + 64 + k];
      pp += w2 * W_edge[k];
      qq += w2 * b_edge[k];
      float w1 = W_el[h * 128 + k];
      float base = wte[k] + wte[64 + k] + bi0[k] + bi1[k];
      s0 += w1 * base;
      s1 += w1 * Wi0[k];
      s2 += w1 * Wi1[k];
    }
    p[h] = pp; q[h] = qq + b_el[h];
    c0[h] = s0; c1[h] = s1; c2[h] = s2;
  }
}

// ---- CSR build (once per call) ----
__global__ __launch_bounds__(256) void k_hist(const int* __restrict__ eidx,
                                              int* __restrict__ deg, int E) {
  int e = blockIdx.x * 256 + threadIdx.x;
  if (e < E) atomicAdd(&deg[eidx[E + e]], 1);
}

// per-512-chunk inclusive scan (off stays chunk-local; consumers add bsum)
__global__ __launch_bounds__(256) void k_scan1(const int* __restrict__ deg,
                                               int* __restrict__ off,
                                               int* __restrict__ bsum, int N) {
  __shared__ int s[256];
  int b = blockIdx.x, t = threadIdx.x;
  int i0 = b * 512 + t * 2;
  int v0 = (i0 < N) ? deg[i0] : 0;
  int v1 = (i0 + 1 < N) ? deg[i0 + 1] : 0;
  int sum = v0 + v1;
  s[t] = sum;
  __syncthreads();
  for (int d = 1; d < 256; d <<= 1) {
    int val = (t >= d) ? s[t - d] : 0;
    __syncthreads();
    s[t] += val;
    __syncthreads();
  }
  int excl = s[t] - sum;
  if (i0 < N) off[i0] = excl + v0;
  if (i0 + 1 < N) off[i0 + 1] = excl + v0 + v1;
  if (t == 255) bsum[b] = s[t];
}

// exclusive scan of block sums (nb <= 128)
__global__ void k_scan2(int* __restrict__ bsum, int nb) {
  __shared__ int s[128];
  int t = threadIdx.x;
  int v = (t < nb) ? bsum[t] : 0;
  s[t] = v;
  __syncthreads();
  for (int d = 1; d < 128; d <<= 1) {
    int val = (t >= d) ? s[t - d] : 0;
    __syncthreads();
    s[t] += val;
    __syncthreads();
  }
  if (t < nb) bsum[t] = s[t] - v;
}

// spack.x = row | (col&15)<<27 ; spack.y = dist bits   (16-node tiles)
__global__ __launch_bounds__(256) void k_scatter(const int* __restrict__ eidx,
                                                 const float* __restrict__ dist,
                                                 const int* __restrict__ off,
                                                 const int* __restrict__ bsum,
                                                 int* __restrict__ cur,
                                                 uint2* __restrict__ spack, int E) {
  int e = blockIdx.x * 256 + threadIdx.x;
  if (e >= E) return;
  int c = eidx[E + e];
  int base = (c == 0) ? 0 : (off[c - 1] + bsum[(c - 1) >> 9]);
  int pos = base + atomicAdd(&cur[c], 1);
  spack[pos] = make_uint2((unsigned)eidx[e] | ((unsigned)(c & 15) << 27),
                          __float_as_uint(dist[e]));
}

// Fused per-layer kernel. MODE 0: layer0 (x,y closed form, write y_next)
//                         MODE 1: mid (y gather, write y_next)
//                         MODE 2: last (y gather, fused out-proj, no x store)
template <int MODE>
__global__ __launch_bounds__(256) void k_node(
    const int* __restrict__ off, const int* __restrict__ bsum,
    const uint2* __restrict__ spack,
    const float* __restrict__ p, const float* __restrict__ q,
    const float* __restrict__ c0, const float* __restrict__ c1,
    const float* __restrict__ c2,
    const float* __restrict__ v0, const float* __restrict__ v1,
    const float* __restrict__ wte,
    const float* __restrict__ Wi0, const float* __restrict__ bi0,
    const float* __restrict__ Wi1, const float* __restrict__ bi1,
    float* __restrict__ x, unsigned short* __restrict__ y_bf,
    const int* __restrict__ batch, const float* __restrict__ u,
    const unsigned short* __restrict__ W1b, const unsigned short* __restrict__ W2b,
    const unsigned short* __restrict__ Welb,
    const float* __restrict__ b_n1, const float* __restrict__ b_n2,
    unsigned* __restrict__ xu_enc,
    float* __restrict__ bmaxA, float* __restrict__ bmaxB,
    int* __restrict__ bgidA, int* __restrict__ bgidB,
    const float* __restrict__ Wo0, const float* __restrict__ bo0,
    const float* __restrict__ Wo1, const float* __restrict__ bo1,
    float* __restrict__ outp, int N) {
  __shared__ __align__(16) char inb[16 * 384];  // [16][192] bf16 (xnb aliases)
  __shared__ __align__(16) char h1T[16 * 512];  // [16][256] bf16 (aggT/ow alias)
  __shared__ uint2 smeta[256];                  // 4 waves x 64 private slices
  __shared__ int sgb[16];
  int t = threadIdx.x;
  int n0 = blockIdx.x * 16;
  int lane = t & 63, wv = t >> 6;
  int lr = lane & 15;
  int lk8 = (lane >> 4) << 3;
  int jo = (lane >> 4) << 2;
  int swzr = (lr & 7) << 4;
  int h0 = wv * 16 + jo;

  // ---- x in stage-2 fragment layout (MODE 0: closed form); u gather; sgb ----
  float4 xo;
  {
    int node = n0 + lr;
    if (MODE == 0) {
      float4 wA = *(const float4*)(wte + h0);
      float4 wB = *(const float4*)(wte + 64 + h0);
      float4 bA = *(const float4*)(bi0 + h0);
      float4 bB = *(const float4*)(bi1 + h0);
      float4 w0v = *(const float4*)(Wi0 + h0);
      float4 w1v = *(const float4*)(Wi1 + h0);
      float a = (node < N) ? v0[node] : 0.f;
      float b = (node < N) ? v1[node] : 0.f;
      xo.x = wA.x + wB.x + bA.x + bB.x + a * w0v.x + b * w1v.x;
      xo.y = wA.y + wB.y + bA.y + bB.y + a * w0v.y + b * w1v.y;
      xo.z = wA.z + wB.z + bA.z + bB.z + a * w0v.z + b * w1v.z;
      xo.w = wA.w + wB.w + bA.w + bB.w + a * w0v.w + b * w1v.w;
    } else {
      xo = (node < N) ? *(const float4*)(x + (size_t)node * 64 + h0)
                      : make_float4(0.f, 0.f, 0.f, 0.f);
    }
  }
  int nd_s = t >> 3, ko = t & 7;   // valid for t < 128
  float4 ua = make_float4(0.f, 0.f, 0.f, 0.f), ub = ua;
  if (t < 128) {
    int node_s = n0 + nd_s;
    if (node_s < N) {
      int g = batch[node_s];
      const float4* u4 = (const float4*)u;
      ua = u4[g * 16 + ko * 2];
      ub = u4[g * 16 + ko * 2 + 1];
    }
  }
  if (t < 16) sgb[t] = batch[min(n0 + t, N - 1)];

  // ---- zero agg tile (aliases h1T) ----
  int* aggi = (int*)h1T;  // [16][64] fp32-as-int, msg >= 0
#pragma unroll
  for (int i = 0; i < 4; ++i) aggi[t + i * 256] = 0;

  // ---- write x (from regs) and u sections of inb ----
  {
    int nd = lr;
    unsigned lo = (unsigned)f2bf(xo.x) | ((unsigned)f2bf(xo.y) << 16);
    unsigned hi = (unsigned)f2bf(xo.z) | ((unsigned)f2bf(xo.w) << 16);
    *(uint2*)(inb + nd * 384 + ((128 + h0 * 2) ^ ((nd & 7) << 4))) = make_uint2(lo, hi);
  }
  if (t < 128) {
    int swz = (nd_s & 7) << 4;
    uint4 uv;
    uv.x = f2bf(ua.x) | ((unsigned)f2bf(ua.y) << 16);
    uv.y = f2bf(ua.z) | ((unsigned)f2bf(ua.w) << 16);
    uv.z = f2bf(ub.x) | ((unsigned)f2bf(ub.y) << 16);
    uv.w = f2bf(ub.z) | ((unsigned)f2bf(ub.w) << 16);
    *(uint4*)(inb + nd_s * 384 + ((256 + ko * 16) ^ swz)) = uv;
  }
  __syncthreads();  // aggi zeroed before any wave aggregates

  // ---- stage 0: DUAL-EDGE half-wave aggregation (barrier-free) ----
  {
    int last = min(n0 + 15, N - 1);
    int ebase = (n0 == 0) ? 0 : (off[n0 - 1] + bsum[(n0 - 1) >> 9]);
    int eend = off[last] + bsum[last >> 9];
    int total = eend - ebase;
    int q4 = total >> 2;
    int wb = ebase + wv * q4;
    int we = (wv == 3) ? eend : (wb + q4);
    uint2* sm = smeta + wv * 64;   // wave-private slice
    int half = lane >> 5, l31 = lane & 31;
    const unsigned* y32 = (const unsigned*)y_bf + l31;
    float2 p2 = *(const float2*)(p + 2 * l31);
    float2 q2 = *(const float2*)(q + 2 * l31);
    float2 c02 = make_float2(0.f, 0.f), c12 = c02, c22 = c02;
    if (MODE == 0) {
      c02 = *(const float2*)(c0 + 2 * l31);
      c12 = *(const float2*)(c1 + 2 * l31);
      c22 = *(const float2*)(c2 + 2 * l31);
    }
    float m0 = 0.f, m1 = 0.f;
    int ccur = -1;
    uint2 r = make_uint2(0u, 0u);
    if (wb < we) {
      int cnt = min(64, we - wb);
      if (lane < cnt) r = spack[wb + lane];
    }
    for (int cb = wb; cb < we; cb += 64) {
      int ccnt = min(64, we - cb);
      sm[lane] = r;
      int nb = cb + 64;
      if (nb < we) {
        int ncnt = we - nb;
        if (lane < ncnt) r = spack[nb + lane];  // prefetch next chunk
      }
      int nfull = ccnt >> 1;
      int i = 0;
      for (; i + 8 <= nfull; i += 8) {
        uint2 e[8]; unsigned yd[8]; float va[8], vb[8];
#pragma unroll
        for (int k = 0; k < 8; ++k) e[k] = sm[2 * (i + k) + half];
#pragma unroll
        for (int k = 0; k < 8; ++k) {
          unsigned row = e[k].x & 0x07FFFFFFu;
          if (MODE == 0) { va[k] = v0[row]; vb[k] = v1[row]; }
          else yd[k] = y32[row << 5];
        }
#pragma unroll
        for (int k = 0; k < 8; ++k) {
          float y0f, y1f;
          if (MODE == 0) {
            y0f = fmaf(vb[k], c22.x, fmaf(va[k], c12.x, c02.x));
            y1f = fmaf(vb[k], c22.y, fmaf(va[k], c12.y, c02.y));
          } else {
            y0f = __uint_as_float(yd[k] << 16);
            y1f = __uint_as_float(yd[k] & 0xFFFF0000u);
          }
          float d = __uint_as_float(e[k].y);
          float g0 = fmaxf(fmaf(d, p2.x, y0f + q2.x), 0.f);
          float g1 = fmaxf(fmaf(d, p2.y, y1f + q2.y), 0.f);
          int c = (int)(e[k].x >> 27);
          if (c != ccur) {
            if (ccur >= 0) {
              atomicMax(&aggi[ccur * 64 + 2 * l31], __float_as_int(m0));
              atomicMax(&aggi[ccur * 64 + 2 * l31 + 1], __float_as_int(m1));
            }
            ccur = c; m0 = g0; m1 = g1;
          } else { m0 = fmaxf(m0, g0); m1 = fmaxf(m1, g1); }
        }
      }
      for (; 2 * i < ccnt; ++i) {
        int idx = 2 * i + half;
        bool val = idx < ccnt;
        uint2 e = sm[val ? idx : 0];
        unsigned row = e.x & 0x07FFFFFFu;
        float y0f, y1f;
        if (MODE == 0) {
          float a = v0[row], b = v1[row];
          y0f = fmaf(b, c22.x, fmaf(a, c12.x, c02.x));
          y1f = fmaf(b, c22.y, fmaf(a, c12.y, c02.y));
        } else {
          unsigned yd = y32[row << 5];
          y0f = __uint_as_float(yd << 16);
          y1f = __uint_as_float(yd & 0xFFFF0000u);
        }
        float d = __uint_as_float(e.y);
        float g0 = val ? fmaxf(fmaf(d, p2.x, y0f + q2.x), 0.f) : 0.f;
        float g1 = val ? fmaxf(fmaf(d, p2.y, y1f + q2.y), 0.f) : 0.f;
        int c = val ? (int)(e.x >> 27) : ccur;
        if (c != ccur) {
          if (ccur >= 0) {
            atomicMax(&aggi[ccur * 64 + 2 * l31], __float_as_int(m0));
            atomicMax(&aggi[ccur * 64 + 2 * l31 + 1], __float_as_int(m1));
          }
          ccur = c; m0 = g0; m1 = g1;
        } else { m0 = fmaxf(m0, g0); m1 = fmaxf(m1, g1); }
      }
    }
    if (ccur >= 0) {
      atomicMax(&aggi[ccur * 64 + 2 * l31], __float_as_int(m0));
      atomicMax(&aggi[ccur * 64 + 2 * l31 + 1], __float_as_int(m1));
    }
  }
  __syncthreads();

  // ---- agg tile -> inb bf16 (swizzled) ----
  if (t < 128) {
    int swz = (nd_s & 7) << 4;
    const float4* ag4 = (const float4*)(h1T);
    float4 aa = ag4[nd_s * 16 + ko * 2];
    float4 ab = ag4[nd_s * 16 + ko * 2 + 1];
    uint4 av;
    av.x = f2bf(aa.x) | ((unsigned)f2bf(aa.y) << 16);
    av.y = f2bf(aa.z) | ((unsigned)f2bf(aa.w) << 16);
    av.z = f2bf(ab.x) | ((unsigned)f2bf(ab.y) << 16);
    av.w = f2bf(ab.z) | ((unsigned)f2bf(ab.w) << 16);
    *(uint4*)(inb + nd_s * 384 + ((ko * 16) ^ swz)) = av;
  }
  __syncthreads();

  int w = wv;

  // ---- stage 1: h1 = relu(W1 @ in^T + b_n1), O=256 (64/wave), 16 nodes ----
  f32x4 acc[4];
#pragma unroll
  for (int ot = 0; ot < 4; ++ot) acc[ot] = (f32x4){0.f, 0.f, 0.f, 0.f};
  const unsigned short* W1p = W1b + (w * 64 + lr) * 192 + lk8;
#pragma unroll
  for (int ks = 0; ks < 6; ++ks) {
    int kb = ks * 64 + lk8 * 2;
    short8 b0 = *(const short8*)(inb + lr * 384 + (kb ^ swzr));
#pragma unroll
    for (int ot = 0; ot < 4; ++ot) {
      short8 a = *(const short8*)(W1p + ot * (16 * 192) + ks * 32);
      acc[ot] = __builtin_amdgcn_mfma_f32_16x16x32_bf16(a, b0, acc[ot], 0, 0, 0);
    }
  }
  __syncthreads();  // aggT fully read; safe to overwrite h1T
#pragma unroll
  for (int ot = 0; ot < 4; ++ot) {
    int o = w * 64 + ot * 16 + jo;
    float4 bs = *(const float4*)(b_n1 + o);
    int nd = lr;
    unsigned lo = (unsigned)f2bf(fmaxf(acc[ot][0] + bs.x, 0.f)) |
                  ((unsigned)f2bf(fmaxf(acc[ot][1] + bs.y, 0.f)) << 16);
    unsigned hi = (unsigned)f2bf(fmaxf(acc[ot][2] + bs.z, 0.f)) |
                  ((unsigned)f2bf(fmaxf(acc[ot][3] + bs.w, 0.f)) << 16);
    *(uint2*)(h1T + nd * 512 + ((o * 2) ^ ((nd & 7) << 4))) = make_uint2(lo, hi);
  }
  __syncthreads();

  // ---- stage 2: x_new = x + W2 @ h1^T + b_n2 (x from regs) ----
  f32x4 acc2 = (f32x4){0.f, 0.f, 0.f, 0.f};
  const unsigned short* W2p = W2b + (w * 16 + lr) * 256 + lk8;
#pragma unroll
  for (int ks = 0; ks < 8; ++ks) {
    short8 a = *(const short8*)(W2p + ks * 32);
    int kb = ks * 64 + lk8 * 2;
    short8 b0 = *(const short8*)(h1T + lr * 512 + (kb ^ swzr));
    acc2 = __builtin_amdgcn_mfma_f32_16x16x32_bf16(a, b0, acc2, 0, 0, 0);
  }
  float4 b2 = *(const float4*)(b_n2 + h0);
  char* xnb = inb;  // alias
  float4 xn;
  {
    int nd = lr;
    int node = n0 + nd;
    xn.x = xo.x + acc2[0] + b2.x;
    xn.y = xo.y + acc2[1] + b2.y;
    xn.z = xo.z + acc2[2] + b2.z;
    xn.w = xo.w + acc2[3] + b2.w;
    if (node >= N) xn = make_float4(0.f, 0.f, 0.f, 0.f);
    if (MODE != 2 && node < N) *(float4*)(x + (size_t)node * 64 + h0) = xn;
    if (MODE != 2) {
      unsigned lo = (unsigned)f2bf(xn.x) | ((unsigned)f2bf(xn.y) << 16);
      unsigned hi = (unsigned)f2bf(xn.z) | ((unsigned)f2bf(xn.w) << 16);
      *(uint2*)(xnb + nd * 128 + ((h0 * 2) ^ ((nd & 7) << 4))) = make_uint2(lo, hi);
    }
  }

  // ---- per-graph max partials -> disjoint scratch ----
  {
    const float NEG = -__builtin_huge_valf();
    int gA = sgb[0], gB = sgb[15];
    float a0 = NEG, a1 = NEG, a2 = NEG, a3 = NEG;
    float e0 = NEG, e1 = NEG, e2 = NEG, e3 = NEG;
    {
      int nd = lr;
      if (n0 + nd < N) {
        int g = sgb[nd];
        if (g == gA) {
          a0 = xn.x; a1 = xn.y; a2 = xn.z; a3 = xn.w;
        } else if (g == gB) {
          e0 = xn.x; e1 = xn.y; e2 = xn.z; e3 = xn.w;
        } else {  // >2 graphs in tile: rare fallback
          unsigned* xe = xu_enc + g * 64 + h0;
          atomicMax(xe + 0, enc_ordered(xn.x));
          atomicMax(xe + 1, enc_ordered(xn.y));
          atomicMax(xe + 2, enc_ordered(xn.z));
          atomicMax(xe + 3, enc_ordered(xn.w));
        }
      }
    }
#pragma unroll
    for (int msk = 1; msk <= 8; msk <<= 1) {
      a0 = fmaxf(a0, __shfl_xor(a0, msk)); a1 = fmaxf(a1, __shfl_xor(a1, msk));
      a2 = fmaxf(a2, __shfl_xor(a2, msk)); a3 = fmaxf(a3, __shfl_xor(a3, msk));
      e0 = fmaxf(e0, __shfl_xor(e0, msk)); e1 = fmaxf(e1, __shfl_xor(e1, msk));
      e2 = fmaxf(e2, __shfl_xor(e2, msk)); e3 = fmaxf(e3, __shfl_xor(e3, msk));
    }
    if (lr == 0) {
      size_t base = (size_t)blockIdx.x * 64 + h0;
      bmaxA[base + 0] = a0; bmaxA[base + 1] = a1;
      bmaxA[base + 2] = a2; bmaxA[base + 3] = a3;
      bmaxB[base + 0] = e0; bmaxB[base + 1] = e1;
      bmaxB[base + 2] = e2; bmaxB[base + 3] = e3;
    }
    if (t == 0) {
      bgidA[blockIdx.x] = gA;
      bgidB[blockIdx.x] = (gB == gA) ? -1 : gB;
    }
  }
  __syncthreads();

  if (MODE != 2) {
    // ---- stage 3: y_next = Welb @ x_new^T (bf16 out) ----
    f32x4 acc3 = (f32x4){0.f, 0.f, 0.f, 0.f};
    const unsigned short* W3p = Welb + (w * 16 + lr) * 64 + lk8;
#pragma unroll
    for (int ks = 0; ks < 2; ++ks) {
      short8 a = *(const short8*)(W3p + ks * 32);
      int kb = ks * 64 + lk8 * 2;
      short8 b0 = *(const short8*)(xnb + lr * 128 + (kb ^ swzr));
      acc3 = __builtin_amdgcn_mfma_f32_16x16x32_bf16(a, b0, acc3, 0, 0, 0);
    }
    int o0 = w * 16 + jo;
    int node = n0 + lr;
    if (node < N) {
      unsigned lo = (unsigned)f2bf(acc3[0]) | ((unsigned)f2bf(acc3[1]) << 16);
      unsigned hi = (unsigned)f2bf(acc3[2]) | ((unsigned)f2bf(acc3[3]) << 16);
      *(uint2*)(y_bf + (size_t)node * 64 + o0) = make_uint2(lo, hi);
    }
  } else {
    // ---- fused output projection ----
    float4 w0 = *(const float4*)(Wo0 + h0);
    float4 w1 = *(const float4*)(Wo1 + h0);
    float* ow = (float*)h1T;  // [4 waves][2 outs][16 nodes]
    {
      float p0 = xn.x * w0.x + xn.y * w0.y + xn.z * w0.z + xn.w * w0.w;
      float p1 = xn.x * w1.x + xn.y * w1.y + xn.z * w1.z + xn.w * w1.w;
      p0 += __shfl_xor(p0, 16); p0 += __shfl_xor(p0, 32);
      p1 += __shfl_xor(p1, 16); p1 += __shfl_xor(p1, 32);
      if (lane < 16) {
        ow[w * 32 + 0 + lr] = p0;
        ow[w * 32 + 16 + lr] = p1;
      }
    }
    __syncthreads();
    if (t < 32) {
      int oi = t >> 4, nd = t & 15;
      int node = n0 + nd;
      if (node < N) {
        float v = ow[0 * 32 + oi * 16 + nd] + ow[1 * 32 + oi * 16 + nd] +
                  ow[2 * 32 + oi * 16 + nd] + ow[3 * 32 + oi * 16 + nd];
        v += (oi ? bo1[0] : bo0[0]);
        outp[(size_t)oi * N + node] = v;
      }
    }
  }
}

// per-graph (256 threads): parallel partial-reduce + split-K GEMVs + LSTM
__global__ __launch_bounds__(256) void k_graph(const int* __restrict__ gstart,
                                               const int* __restrict__ gend,
                                               const float* __restrict__ bmaxA,
                                               const float* __restrict__ bmaxB,
                                               const int* __restrict__ bgidA,
                                               const int* __restrict__ bgidB,
                                               unsigned* __restrict__ xu_enc,
                                               float* __restrict__ u,
                                               const float* __restrict__ W_gl,
                                               const float* __restrict__ b_gl,
                                               const float* __restrict__ W_ih,
                                               const float* __restrict__ b_ih,
                                               const float* __restrict__ b_hh,
                                               float* __restrict__ c_out) {
  __shared__ float red[4][3][64];
  __shared__ float xu_s[64], us[64], un[64];
  int g = blockIdx.x;
  int t = threadIdx.x, h = t & 63, qd = t >> 6;
  const float NEG = -__builtin_huge_valf();

  // strided tile-partial reduce across 4 waves (16-node tiles)
  float m = NEG;
  int gs = gstart[g], ge = gend[g];
  if (gs < ge) {
    int bs = gs >> 4, be = (ge - 1) >> 4;
    for (int b = bs + qd; b <= be; b += 4) {
      if (bgidA[b] == g) m = fmaxf(m, bmaxA[(size_t)b * 64 + h]);
      if (bgidB[b] == g) m = fmaxf(m, bmaxB[(size_t)b * 64 + h]);
    }
  }
  red[qd][0][h] = m;
  __syncthreads();
  if (qd == 0) {
    m = fmaxf(fmaxf(red[0][0][h], red[1][0][h]), fmaxf(red[2][0][h], red[3][0][h]));
    unsigned Ev = xu_enc[g * 64 + h];  // fallback decode + reset
    float fd = (Ev & 0x80000000u) ? __uint_as_float(Ev & 0x7FFFFFFFu)
                                  : __uint_as_float(~Ev);
    m = fmaxf(m, fd);
    xu_enc[g * 64 + h] = 0x007FFFFFu;
    xu_s[h] = isfinite(m) ? m : 0.f;
    us[h] = u[g * 64 + h];
  }
  __syncthreads();

  // W_gl GEMV split-K: pre[h] = b_gl[h] + [xu|us] . W_gl[h]
  float pre = 0.f;
  {
    const float* Wrow = W_gl + h * 128 + qd * 32;
    const float* src = (qd < 2) ? (xu_s + qd * 32) : (us + (qd - 2) * 32);
#pragma unroll 8
    for (int k = 0; k < 32; ++k) pre += src[k] * Wrow[k];
  }
  red[qd][0][h] = pre;
  __syncthreads();
  if (qd == 0) {
    float prs = red[0][0][h] + red[1][0][h] + red[2][0][h] + red[3][0][h] + b_gl[h];
    un[h] = us[h] + fmaxf(prs, 0.f);
  }
  __syncthreads();

  // LSTM gates split-K (16 each over 4 waves)
  float gi = 0.f, gg = 0.f, go = 0.f;
#pragma unroll 4
  for (int k = qd * 16; k < qd * 16 + 16; ++k) {
    float uv = un[k];
    gi += uv * W_ih[h * 64 + k];
    gg += uv * W_ih[(128 + h) * 64 + k];
    go += uv * W_ih[(192 + h) * 64 + k];
  }
  red[qd][0][h] = gi; red[qd][1][h] = gg; red[qd][2][h] = go;
  __syncthreads();
  if (qd == 0) {
    gi = red[0][0][h] + red[1][0][h] + red[2][0][h] + red[3][0][h] + b_ih[h] + b_hh[h];
    gg = red[0][1][h] + red[1][1][h] + red[2][1][h] + red[3][1][h] +
         b_ih[128 + h] + b_hh[128 + h];
    go = red[0][2][h] + red[1][2][h] + red[2][2][h] + red[3][2][h] +
         b_ih[192 + h] + b_hh[192 + h];
    float cc = (1.f / (1.f + expf(-gi))) * tanhf(gg);
    float u2v = (1.f / (1.f + expf(-go))) * tanhf(cc);
    c_out[g * 64 + h] = cc;
    u[g * 64 + h] = u2v;
  }
}

extern "C" void kernel_launch(void* const* d_in, const int* in_sizes, int n_in,
                              void* d_out, int out_size, void* d_ws, size_t ws_size,
                              hipStream_t stream) {
  const float* v0 = (const float*)d_in[0];
  const float* v1 = (const float*)d_in[1];
  const float* dist = (const float*)d_in[2];
  const int* eidx = (const int*)d_in[3];
  const int* batch = (const int*)d_in[4];
  const float* wte = (const float*)d_in[6];
  const float* Wi0 = (const float*)d_in[7];
  const float* bi0 = (const float*)d_in[8];
  const float* Wi1 = (const float*)d_in[9];
  const float* bi1 = (const float*)d_in[10];
  const float* Wo0 = (const float*)d_in[11];
  const float* bo0 = (const float*)d_in[12];
  const float* Wo1 = (const float*)d_in[13];
  const float* bo1 = (const float*)d_in[14];
  const float* W_edge = (const float*)d_in[15];
  const float* b_edge = (const float*)d_in[16];
  const float* W_el = (const float*)d_in[17];
  const float* b_el = (const float*)d_in[18];
  const float* W_n1 = (const float*)d_in[19];
  const float* b_n1 = (const float*)d_in[20];
  const float* W_n2 = (const float*)d_in[21];
  const float* b_n2 = (const float*)d_in[22];
  const float* W_gl = (const float*)d_in[23];
  const float* b_gl = (const float*)d_in[24];
  const float* W_ih = (const float*)d_in[25];
  const float* b_ih = (const float*)d_in[27];
  const float* b_hh = (const float*)d_in[28];

  const int N = in_sizes[0];
  const int E = in_sizes[2];
  const int NH = N * 64;
  const int NB512 = (N + 511) / 512;
  const int nblk = (N + 15) / 16;

  float* ws = (float*)d_ws;
  float* x = ws;                                   // NH
  float* u = x + NH;                               // 4096
  unsigned* xu_enc = (unsigned*)(u + 4096);        // 4096
  float* p = (float*)(xu_enc + 4096);
  float* q = p + 64;
  float* c0 = q + 64;
  float* c1 = c0 + 64;
  float* c2 = c1 + 64;
  unsigned short* W1b = (unsigned short*)(c2 + 64);  // 49152
  unsigned short* W2b = W1b + 49152;                 // 16384
  unsigned short* Welb = W2b + 16384;                // 4096
  unsigned short* y_bf = Welb + 4096;                // NH
  int* deg = (int*)(y_bf + NH);                      // N
  int* off = deg + N;                                // N
  int* cur = off + N;                                // N
  int* bsum = cur + N;                               // 128
  int* gstart = bsum + 128;                          // 64
  int* gend = gstart + 64;                           // 64
  int* bgidA = gend + 64;                            // nblk
  int* bgidB = bgidA + nblk;                         // nblk
  float* bmaxA = (float*)(bgidB + nblk);             // nblk*64
  float* bmaxB = bmaxA + (size_t)nblk * 64;          // nblk*64
  uint2* spack = (uint2*)(((size_t)(bmaxB + (size_t)nblk * 64) + 15) & ~(size_t)15);  // E

  float* outp = (float*)d_out;

  k_init<<<(77824 + 3 * N + 64 + 255) / 256, 256, 0, stream>>>(
      v0, v1, wte, Wi0, bi0, Wi1, bi1, batch, gstart, gend,
      u, xu_enc, W1b, W2b, Welb, W_n1, W_n2, W_el, b_el, W_edge, b_edge,
      p, q, c0, c1, c2, deg, cur, N);
  k_hist<<<(E + 255) / 256, 256, 0, stream>>>(eidx, deg, E);
  k_scan1<<<NB512, 256, 0, stream>>>(deg, off, bsum, N);
  k_scan2<<<1, 128, 0, stream>>>(bsum, NB512);
  k_scatter<<<(E + 255) / 256, 256, 0, stream>>>(eidx, dist, off, bsum, cur, spack, E);

  for (int l = 0; l < 4; ++l) {
    if (l == 0) {
      k_node<0><<<nblk, 256, 0, stream>>>(off, bsum, spack, p, q, c0, c1, c2, v0, v1,
                                          wte, Wi0, bi0, Wi1, bi1,
                                          x, y_bf, batch, u, W1b, W2b, Welb, b_n1, b_n2,
                                          xu_enc, bmaxA, bmaxB, bgidA, bgidB,
                                          Wo0, bo0, Wo1, bo1, outp, N);
    } else if (l < 3) {
      k_node<1><<<nblk, 256, 0, stream>>>(off, bsum, spack, p, q, c0, c1, c2, v0, v1,
                                          wte, Wi0, bi0, Wi1, bi1,
                                          x, y_bf, batch, u, W1b, W2b, Welb, b_n1, b_n2,
                                          xu_enc, bmaxA, bmaxB, bgidA, bgidB,
                                          Wo0, bo0, Wo1, bo1, outp, N);
    } else {
      k_node<2><<<nblk, 256, 0, stream>>>(off, bsum, spack, p, q, c0, c1, c2, v0, v1,
                                          wte, Wi0, bi0, Wi1, bi1,
                                          x, y_bf, batch, u, W1b, W2b, Welb, b_n1, b_n2,
                                          xu_enc, bmaxA, bmaxB, bgidA, bgidB,
                                          Wo0, bo0, Wo1, bo1, outp, N);
    }
    k_graph<<<64, 256, 0, stream>>>(gstart, gend, bmaxA, bmaxB, bgidA, bgidB,
                                    xu_enc, u, W_gl, b_gl, W_ih, b_ih, b_hh,
                                    outp + 2 * N + l * 4096);
  }
}

// Round 12
// 309.467 us; speedup vs baseline: 1.3233x; 1.3233x over previous
//
#include <hip/hip_runtime.h>

// GraphTemporal: N=50000, E=500000, B=64, H=64, L=4 shared layers.
// msg = relu(y[row] + dist*p + q), y = x @ W_el[:, :64].T
// Layer 0: y AND x computed on the fly from v0,v1 (rank-2 closed form).
// 32-node tiles; stage1/2 split into two o-halves -> h1 LDS 8KB, total ~22.7KB
// -> 7 blocks/CU resident (latency hiding). Edge aggregation fused (stage 0):
// dual-edge half-wave (32 lanes/edge, dword=2ch/lane), per-wave contiguous
// edge quarters, wave-private LDS meta slice + reg prefetch, running-max.
// Per-graph max via disjoint per-tile scratch reduced in k_graph (256 thr).

typedef __attribute__((ext_vector_type(8))) short short8;
typedef __attribute__((ext_vector_type(4))) float f32x4;

__device__ __forceinline__ unsigned short f2bf(float f) {
  union { float f; unsigned u; } v; v.f = f;
  unsigned r = v.u + 0x7FFFu + ((v.u >> 16) & 1u);
  return (unsigned short)(r >> 16);
}
__device__ __forceinline__ float bf2f(unsigned short s) {
  return __uint_as_float((unsigned)s << 16);
}
__device__ __forceinline__ unsigned enc_ordered(float f) {
  unsigned u = __float_as_uint(f);
  return (u >> 31) ? ~u : (u | 0x80000000u);
}

// fused init: graph ranges, u=0, xu_enc, bf16 weights, deg/cur=0, p/q/c0..c2
__global__ void k_init(const float* __restrict__ v0, const float* __restrict__ v1,
                       const float* __restrict__ wte,
                       const float* __restrict__ Wi0, const float* __restrict__ bi0,
                       const float* __restrict__ Wi1, const float* __restrict__ bi1,
                       const int* __restrict__ batch,
                       int* __restrict__ gstart, int* __restrict__ gend,
                       float* __restrict__ u, unsigned* __restrict__ xu_enc,
                       unsigned short* __restrict__ W1b, unsigned short* __restrict__ W2b,
                       unsigned short* __restrict__ Welb,
                       const float* __restrict__ W_n1, const float* __restrict__ W_n2,
                       const float* __restrict__ W_el,
                       const float* __restrict__ b_el,
                       const float* __restrict__ W_edge, const float* __restrict__ b_edge,
                       float* __restrict__ p, float* __restrict__ q,
                       float* __restrict__ c0, float* __restrict__ c1,
                       float* __restrict__ c2,
                       int* __restrict__ deg, int* __restrict__ cur, int N) {
  int i = blockIdx.x * 256 + threadIdx.x;
  if (i < 4096) {
    u[i] = 0.f;
  } else if (i < 8192) {
    xu_enc[i - 4096] = 0x007FFFFFu;  // enc(-inf)
  } else if (i < 8192 + 49152) {
    int j = i - 8192;                 // W_n1 [256][192]
    W1b[j] = f2bf(W_n1[j]);
  } else if (i < 8192 + 49152 + 16384) {
    int j = i - 57344;                // W_n2 [64][256]
    W2b[j] = f2bf(W_n2[j]);
  } else if (i < 77824) {
    int j = i - 73728;                // W_el[:, :64] compact stride 64
    Welb[j] = f2bf(W_el[(j >> 6) * 128 + (j & 63)]);
  } else if (i < 77824 + N) {
    deg[i - 77824] = 0;
  } else if (i < 77824 + 2 * N) {
    cur[i - 77824 - N] = 0;
  } else if (i < 77824 + 3 * N) {
    int n = i - 77824 - 2 * N;        // graph range detection (unique writer)
    int bg = batch[n];
    if (n == 0 || batch[n - 1] != bg) gstart[bg] = n;
    if (n == N - 1 || batch[n + 1] != bg) gend[bg] = n + 1;
  } else if (i < 77824 + 3 * N + 64) {
    int h = i - 77824 - 3 * N;
    float pp = 0.f, qq = 0.f, s0 = 0.f, s1 = 0.f, s2 = 0.f;
    for (int k = 0; k < 64; ++k) {
      float w2 = W_el[h * 128 + 64 + k];
      pp += w2 * W_edge[k];
      qq += w2 * b_edge[k];
      float w1 = W_el[h * 128 + k];
      float base = wte[k] + wte[64 + k] + bi0[k] + bi1[k];
      s0 += w1 * base;
      s1 += w1 * Wi0[k];
      s2 += w1 * Wi1[k];
    }
    p[h] = pp; q[h] = qq + b_el[h];
    c0[h] = s0; c1[h] = s1; c2[h] = s2;
  }
}

// ---- CSR build (once per call) ----
__global__ __launch_bounds__(256) void k_hist(const int* __restrict__ eidx,
                                              int* __restrict__ deg, int E) {
  int e = blockIdx.x * 256 + threadIdx.x;
  if (e < E) atomicAdd(&deg[eidx[E + e]], 1);
}

// per-512-chunk inclusive scan (off stays chunk-local; consumers add bsum)
__global__ __launch_bounds__(256) void k_scan1(const int* __restrict__ deg,
                                               int* __restrict__ off,
                                               int* __restrict__ bsum, int N) {
  __shared__ int s[256];
  int b = blockIdx.x, t = threadIdx.x;
  int i0 = b * 512 + t * 2;
  int v0 = (i0 < N) ? deg[i0] : 0;
  int v1 = (i0 + 1 < N) ? deg[i0 + 1] : 0;
  int sum = v0 + v1;
  s[t] = sum;
  __syncthreads();
  for (int d = 1; d < 256; d <<= 1) {
    int val = (t >= d) ? s[t - d] : 0;
    __syncthreads();
    s[t] += val;
    __syncthreads();
  }
  int excl = s[t] - sum;
  if (i0 < N) off[i0] = excl + v0;
  if (i0 + 1 < N) off[i0 + 1] = excl + v0 + v1;
  if (t == 255) bsum[b] = s[t];
}

// exclusive scan of block sums (nb <= 128)
__global__ void k_scan2(int* __restrict__ bsum, int nb) {
  __shared__ int s[128];
  int t = threadIdx.x;
  int v = (t < nb) ? bsum[t] : 0;
  s[t] = v;
  __syncthreads();
  for (int d = 1; d < 128; d <<= 1) {
    int val = (t >= d) ? s[t - d] : 0;
    __syncthreads();
    s[t] += val;
    __syncthreads();
  }
  if (t < nb) bsum[t] = s[t] - v;
}

// spack.x = row | (col&31)<<27 ; spack.y = dist bits
__global__ __launch_bounds__(256) void k_scatter(const int* __restrict__ eidx,
                                                 const float* __restrict__ dist,
                                                 const int* __restrict__ off,
                                                 const int* __restrict__ bsum,
                                                 int* __restrict__ cur,
                                                 uint2* __restrict__ spack, int E) {
  int e = blockIdx.x * 256 + threadIdx.x;
  if (e >= E) return;
  int c = eidx[E + e];
  int base = (c == 0) ? 0 : (off[c - 1] + bsum[(c - 1) >> 9]);
  int pos = base + atomicAdd(&cur[c], 1);
  spack[pos] = make_uint2((unsigned)eidx[e] | ((unsigned)(c & 31) << 27),
                          __float_as_uint(dist[e]));
}

// Fused per-layer kernel. MODE 0: layer0 (x,y closed form, write y_next)
//                         MODE 1: mid (y gather, write y_next)
//                         MODE 2: last (y gather, fused out-proj, no x store)
template <int MODE>
__global__ __launch_bounds__(256) void k_node(
    const int* __restrict__ off, const int* __restrict__ bsum,
    const uint2* __restrict__ spack,
    const float* __restrict__ p, const float* __restrict__ q,
    const float* __restrict__ c0, const float* __restrict__ c1,
    const float* __restrict__ c2,
    const float* __restrict__ v0, const float* __restrict__ v1,
    const float* __restrict__ wte,
    const float* __restrict__ Wi0, const float* __restrict__ bi0,
    const float* __restrict__ Wi1, const float* __restrict__ bi1,
    float* __restrict__ x, unsigned short* __restrict__ y_bf,
    const int* __restrict__ batch, const float* __restrict__ u,
    const unsigned short* __restrict__ W1b, const unsigned short* __restrict__ W2b,
    const unsigned short* __restrict__ Welb,
    const float* __restrict__ b_n1, const float* __restrict__ b_n2,
    unsigned* __restrict__ xu_enc,
    float* __restrict__ bmaxA, float* __restrict__ bmaxB,
    int* __restrict__ bgidA, int* __restrict__ bgidB,
    const float* __restrict__ Wo0, const float* __restrict__ bo0,
    const float* __restrict__ Wo1, const float* __restrict__ bo1,
    float* __restrict__ outp, int N) {
  __shared__ __align__(16) char inb[32 * 384];  // [32][192] bf16 (xnb aliases)
  __shared__ __align__(16) char h1h[32 * 256];  // [32][128] bf16 half (aggT/ow alias)
  __shared__ uint2 smeta[256];                  // 4 waves x 64 private slices
  __shared__ int sgb[32];
  int t = threadIdx.x;
  int n0 = blockIdx.x * 32;
  int lane = t & 63, wv = t >> 6;
  int lr = lane & 15;
  int lk8 = (lane >> 4) << 3;
  int jo = (lane >> 4) << 2;
  int swzr = (lr & 7) << 4;
  int h0 = wv * 16 + jo;

  // ---- x in stage-2 fragment layout (MODE 0: closed form); u gather; sgb ----
  float4 xo[2];
  if (MODE == 0) {
    float4 wA = *(const float4*)(wte + h0);
    float4 wB = *(const float4*)(wte + 64 + h0);
    float4 bA = *(const float4*)(bi0 + h0);
    float4 bB = *(const float4*)(bi1 + h0);
    float4 w0v = *(const float4*)(Wi0 + h0);
    float4 w1v = *(const float4*)(Wi1 + h0);
    float4 cb = make_float4(wA.x + wB.x + bA.x + bB.x, wA.y + wB.y + bA.y + bB.y,
                            wA.z + wB.z + bA.z + bB.z, wA.w + wB.w + bA.w + bB.w);
#pragma unroll
    for (int nt = 0; nt < 2; ++nt) {
      int node = n0 + nt * 16 + lr;
      float a = (node < N) ? v0[node] : 0.f;
      float b = (node < N) ? v1[node] : 0.f;
      xo[nt].x = cb.x + a * w0v.x + b * w1v.x;
      xo[nt].y = cb.y + a * w0v.y + b * w1v.y;
      xo[nt].z = cb.z + a * w0v.z + b * w1v.z;
      xo[nt].w = cb.w + a * w0v.w + b * w1v.w;
    }
  } else {
#pragma unroll
    for (int nt = 0; nt < 2; ++nt) {
      int node = n0 + nt * 16 + lr;
      xo[nt] = (node < N) ? *(const float4*)(x + (size_t)node * 64 + h0)
                          : make_float4(0.f, 0.f, 0.f, 0.f);
    }
  }
  int nd_s = t >> 3, ko = t & 7;
  int node_s = n0 + nd_s;
  float4 ua = make_float4(0.f, 0.f, 0.f, 0.f), ub = ua;
  if (node_s < N) {
    int g = batch[node_s];
    const float4* u4 = (const float4*)u;
    ua = u4[g * 16 + ko * 2];
    ub = u4[g * 16 + ko * 2 + 1];
  }
  if (t < 32) sgb[t] = batch[min(n0 + t, N - 1)];

  // ---- zero agg tile (aliases h1h) ----
  int* aggi = (int*)h1h;  // [32][64] fp32-as-int, msg >= 0
#pragma unroll
  for (int i = 0; i < 8; ++i) aggi[t + i * 256] = 0;

  // ---- write x (from regs) and u sections of inb ----
#pragma unroll
  for (int nt = 0; nt < 2; ++nt) {
    int nd = nt * 16 + lr;
    unsigned lo = (unsigned)f2bf(xo[nt].x) | ((unsigned)f2bf(xo[nt].y) << 16);
    unsigned hi = (unsigned)f2bf(xo[nt].z) | ((unsigned)f2bf(xo[nt].w) << 16);
    *(uint2*)(inb + nd * 384 + ((128 + h0 * 2) ^ ((nd & 7) << 4))) = make_uint2(lo, hi);
  }
  {
    int swz = (nd_s & 7) << 4;
    uint4 uv;
    uv.x = f2bf(ua.x) | ((unsigned)f2bf(ua.y) << 16);
    uv.y = f2bf(ua.z) | ((unsigned)f2bf(ua.w) << 16);
    uv.z = f2bf(ub.x) | ((unsigned)f2bf(ub.y) << 16);
    uv.w = f2bf(ub.z) | ((unsigned)f2bf(ub.w) << 16);
    *(uint4*)(inb + nd_s * 384 + ((256 + ko * 16) ^ swz)) = uv;
  }
  __syncthreads();  // aggi zeroed before any wave aggregates

  // ---- stage 0: DUAL-EDGE half-wave aggregation (barrier-free) ----
  {
    int last = min(n0 + 31, N - 1);
    int ebase = (n0 == 0) ? 0 : (off[n0 - 1] + bsum[(n0 - 1) >> 9]);
    int eend = off[last] + bsum[last >> 9];
    int total = eend - ebase;
    int q4 = total >> 2;
    int wb = ebase + wv * q4;
    int we = (wv == 3) ? eend : (wb + q4);
    uint2* sm = smeta + wv * 64;   // wave-private slice
    int half = lane >> 5, l31 = lane & 31;
    const unsigned* y32 = (const unsigned*)y_bf + l31;
    float2 p2 = *(const float2*)(p + 2 * l31);
    float2 q2 = *(const float2*)(q + 2 * l31);
    float2 c02 = make_float2(0.f, 0.f), c12 = c02, c22 = c02;
    if (MODE == 0) {
      c02 = *(const float2*)(c0 + 2 * l31);
      c12 = *(const float2*)(c1 + 2 * l31);
      c22 = *(const float2*)(c2 + 2 * l31);
    }
    float m0 = 0.f, m1 = 0.f;
    int ccur = -1;
    uint2 r = make_uint2(0u, 0u);
    if (wb < we) {
      int cnt = min(64, we - wb);
      if (lane < cnt) r = spack[wb + lane];
    }
    for (int cb = wb; cb < we; cb += 64) {
      int ccnt = min(64, we - cb);
      sm[lane] = r;
      int nb = cb + 64;
      if (nb < we) {
        int ncnt = we - nb;
        if (lane < ncnt) r = spack[nb + lane];  // prefetch next chunk
      }
      int nfull = ccnt >> 1;
      int i = 0;
      for (; i + 8 <= nfull; i += 8) {
        uint2 e[8]; unsigned yd[8]; float va[8], vb[8];
#pragma unroll
        for (int k = 0; k < 8; ++k) e[k] = sm[2 * (i + k) + half];
#pragma unroll
        for (int k = 0; k < 8; ++k) {
          unsigned row = e[k].x & 0x07FFFFFFu;
          if (MODE == 0) { va[k] = v0[row]; vb[k] = v1[row]; }
          else yd[k] = y32[row << 5];
        }
#pragma unroll
        for (int k = 0; k < 8; ++k) {
          float y0f, y1f;
          if (MODE == 0) {
            y0f = fmaf(vb[k], c22.x, fmaf(va[k], c12.x, c02.x));
            y1f = fmaf(vb[k], c22.y, fmaf(va[k], c12.y, c02.y));
          } else {
            y0f = __uint_as_float(yd[k] << 16);
            y1f = __uint_as_float(yd[k] & 0xFFFF0000u);
          }
          float d = __uint_as_float(e[k].y);
          float g0 = fmaxf(fmaf(d, p2.x, y0f + q2.x), 0.f);
          float g1 = fmaxf(fmaf(d, p2.y, y1f + q2.y), 0.f);
          int c = (int)(e[k].x >> 27);
          if (c != ccur) {
            if (ccur >= 0) {
              atomicMax(&aggi[ccur * 64 + 2 * l31], __float_as_int(m0));
              atomicMax(&aggi[ccur * 64 + 2 * l31 + 1], __float_as_int(m1));
            }
            ccur = c; m0 = g0; m1 = g1;
          } else { m0 = fmaxf(m0, g0); m1 = fmaxf(m1, g1); }
        }
      }
      for (; 2 * i < ccnt; ++i) {
        int idx = 2 * i + half;
        bool val = idx < ccnt;
        uint2 e = sm[val ? idx : 0];
        unsigned row = e.x & 0x07FFFFFFu;
        float y0f, y1f;
        if (MODE == 0) {
          float a = v0[row], b = v1[row];
          y0f = fmaf(b, c22.x, fmaf(a, c12.x, c02.x));
          y1f = fmaf(b, c22.y, fmaf(a, c12.y, c02.y));
        } else {
          unsigned yd = y32[row << 5];
          y0f = __uint_as_float(yd << 16);
          y1f = __uint_as_float(yd & 0xFFFF0000u);
        }
        float d = __uint_as_float(e.y);
        float g0 = val ? fmaxf(fmaf(d, p2.x, y0f + q2.x), 0.f) : 0.f;
        float g1 = val ? fmaxf(fmaf(d, p2.y, y1f + q2.y), 0.f) : 0.f;
        int c = val ? (int)(e.x >> 27) : ccur;
        if (c != ccur) {
          if (ccur >= 0) {
            atomicMax(&aggi[ccur * 64 + 2 * l31], __float_as_int(m0));
            atomicMax(&aggi[ccur * 64 + 2 * l31 + 1], __float_as_int(m1));
          }
          ccur = c; m0 = g0; m1 = g1;
        } else { m0 = fmaxf(m0, g0); m1 = fmaxf(m1, g1); }
      }
    }
    if (ccur >= 0) {
      atomicMax(&aggi[ccur * 64 + 2 * l31], __float_as_int(m0));
      atomicMax(&aggi[ccur * 64 + 2 * l31 + 1], __float_as_int(m1));
    }
  }
  __syncthreads();

  // ---- agg tile -> inb bf16 (swizzled) ----
  {
    int swz = (nd_s & 7) << 4;
    const float4* ag4 = (const float4*)(h1h);
    float4 aa = ag4[nd_s * 16 + ko * 2];
    float4 ab = ag4[nd_s * 16 + ko * 2 + 1];
    uint4 av;
    av.x = f2bf(aa.x) | ((unsigned)f2bf(aa.y) << 16);
    av.y = f2bf(aa.z) | ((unsigned)f2bf(aa.w) << 16);
    av.z = f2bf(ab.x) | ((unsigned)f2bf(ab.y) << 16);
    av.w = f2bf(ab.z) | ((unsigned)f2bf(ab.w) << 16);
    *(uint4*)(inb + nd_s * 384 + ((ko * 16) ^ swz)) = av;
  }
  __syncthreads();  // aggi fully read; h1h reusable

  int w = wv;

  // ---- stages 1+2 in two o-halves (h1h 8KB) ----
  f32x4 acc2[2] = {{0.f, 0.f, 0.f, 0.f}, {0.f, 0.f, 0.f, 0.f}};
#pragma unroll
  for (int H = 0; H < 2; ++H) {
    f32x4 acc[2][2];
#pragma unroll
    for (int ot = 0; ot < 2; ++ot)
#pragma unroll
      for (int nt = 0; nt < 2; ++nt) acc[ot][nt] = (f32x4){0.f, 0.f, 0.f, 0.f};
    const unsigned short* W1p = W1b + (size_t)(H * 128 + w * 32 + lr) * 192 + lk8;
#pragma unroll
    for (int ks = 0; ks < 6; ++ks) {
      int kb = ks * 64 + lk8 * 2;
      short8 b0 = *(const short8*)(inb + lr * 384 + (kb ^ swzr));
      short8 b1 = *(const short8*)(inb + (16 + lr) * 384 + (kb ^ swzr));
#pragma unroll
      for (int ot = 0; ot < 2; ++ot) {
        short8 a = *(const short8*)(W1p + ot * (16 * 192) + ks * 32);
        acc[ot][0] = __builtin_amdgcn_mfma_f32_16x16x32_bf16(a, b0, acc[ot][0], 0, 0, 0);
        acc[ot][1] = __builtin_amdgcn_mfma_f32_16x16x32_bf16(a, b1, acc[ot][1], 0, 0, 0);
      }
    }
#pragma unroll
    for (int ot = 0; ot < 2; ++ot) {
      int o = H * 128 + w * 32 + ot * 16 + jo;
      float4 bs = *(const float4*)(b_n1 + o);
      int ol = (w * 32 + ot * 16 + jo) * 2;  // 0..254 within half
#pragma unroll
      for (int nt = 0; nt < 2; ++nt) {
        int nd = nt * 16 + lr;
        unsigned lo = (unsigned)f2bf(fmaxf(acc[ot][nt][0] + bs.x, 0.f)) |
                      ((unsigned)f2bf(fmaxf(acc[ot][nt][1] + bs.y, 0.f)) << 16);
        unsigned hi = (unsigned)f2bf(fmaxf(acc[ot][nt][2] + bs.z, 0.f)) |
                      ((unsigned)f2bf(fmaxf(acc[ot][nt][3] + bs.w, 0.f)) << 16);
        *(uint2*)(h1h + nd * 256 + (ol ^ ((nd & 7) << 4))) = make_uint2(lo, hi);
      }
    }
    __syncthreads();  // h1h half written
    const unsigned short* W2p = W2b + (w * 16 + lr) * 256 + H * 128 + lk8;
#pragma unroll
    for (int ks = 0; ks < 4; ++ks) {
      short8 a = *(const short8*)(W2p + ks * 32);
      int kb = ks * 64 + lk8 * 2;
      short8 b0 = *(const short8*)(h1h + lr * 256 + (kb ^ swzr));
      short8 b1 = *(const short8*)(h1h + (16 + lr) * 256 + (kb ^ swzr));
      acc2[0] = __builtin_amdgcn_mfma_f32_16x16x32_bf16(a, b0, acc2[0], 0, 0, 0);
      acc2[1] = __builtin_amdgcn_mfma_f32_16x16x32_bf16(a, b1, acc2[1], 0, 0, 0);
    }
    if (H == 0) __syncthreads();  // h1h fully read before half-1 overwrite
  }

  float4 b2 = *(const float4*)(b_n2 + h0);
  char* xnb = inb;  // alias (inb dead after stage-1 half-1)
  float4 xn[2];
#pragma unroll
  for (int nt = 0; nt < 2; ++nt) {
    int nd = nt * 16 + lr;
    int node = n0 + nd;
    xn[nt].x = xo[nt].x + acc2[nt][0] + b2.x;
    xn[nt].y = xo[nt].y + acc2[nt][1] + b2.y;
    xn[nt].z = xo[nt].z + acc2[nt][2] + b2.z;
    xn[nt].w = xo[nt].w + acc2[nt][3] + b2.w;
    if (node >= N) xn[nt] = make_float4(0.f, 0.f, 0.f, 0.f);
    if (MODE != 2 && node < N) *(float4*)(x + (size_t)node * 64 + h0) = xn[nt];
    if (MODE != 2) {
      unsigned lo = (unsigned)f2bf(xn[nt].x) | ((unsigned)f2bf(xn[nt].y) << 16);
      unsigned hi = (unsigned)f2bf(xn[nt].z) | ((unsigned)f2bf(xn[nt].w) << 16);
      *(uint2*)(xnb + nd * 128 + ((h0 * 2) ^ ((nd & 7) << 4))) = make_uint2(lo, hi);
    }
  }

  // ---- per-graph max partials -> disjoint scratch ----
  {
    const float NEG = -__builtin_huge_valf();
    int gA = sgb[0], gB = sgb[31];
    float a0 = NEG, a1 = NEG, a2 = NEG, a3 = NEG;
    float e0 = NEG, e1 = NEG, e2 = NEG, e3 = NEG;
#pragma unroll
    for (int nt = 0; nt < 2; ++nt) {
      int nd = nt * 16 + lr;
      if (n0 + nd < N) {
        int g = sgb[nd];
        if (g == gA) {
          a0 = fmaxf(a0, xn[nt].x); a1 = fmaxf(a1, xn[nt].y);
          a2 = fmaxf(a2, xn[nt].z); a3 = fmaxf(a3, xn[nt].w);
        } else if (g == gB) {
          e0 = fmaxf(e0, xn[nt].x); e1 = fmaxf(e1, xn[nt].y);
          e2 = fmaxf(e2, xn[nt].z); e3 = fmaxf(e3, xn[nt].w);
        } else {  // >2 graphs in block: rare fallback
          unsigned* xe = xu_enc + g * 64 + h0;
          atomicMax(xe + 0, enc_ordered(xn[nt].x));
          atomicMax(xe + 1, enc_ordered(xn[nt].y));
          atomicMax(xe + 2, enc_ordered(xn[nt].z));
          atomicMax(xe + 3, enc_ordered(xn[nt].w));
        }
      }
    }
#pragma unroll
    for (int msk = 1; msk <= 8; msk <<= 1) {
      a0 = fmaxf(a0, __shfl_xor(a0, msk)); a1 = fmaxf(a1, __shfl_xor(a1, msk));
      a2 = fmaxf(a2, __shfl_xor(a2, msk)); a3 = fmaxf(a3, __shfl_xor(a3, msk));
      e0 = fmaxf(e0, __shfl_xor(e0, msk)); e1 = fmaxf(e1, __shfl_xor(e1, msk));
      e2 = fmaxf(e2, __shfl_xor(e2, msk)); e3 = fmaxf(e3, __shfl_xor(e3, msk));
    }
    if (lr == 0) {
      size_t base = (size_t)blockIdx.x * 64 + h0;
      bmaxA[base + 0] = a0; bmaxA[base + 1] = a1;
      bmaxA[base + 2] = a2; bmaxA[base + 3] = a3;
      bmaxB[base + 0] = e0; bmaxB[base + 1] = e1;
      bmaxB[base + 2] = e2; bmaxB[base + 3] = e3;
    }
    if (t == 0) {
      bgidA[blockIdx.x] = gA;
      bgidB[blockIdx.x] = (gB == gA) ? -1 : gB;
    }
  }
  __syncthreads();

  if (MODE != 2) {
    // ---- stage 3: y_next = Welb @ x_new^T (bf16 out) ----
    f32x4 acc3[2] = {{0.f, 0.f, 0.f, 0.f}, {0.f, 0.f, 0.f, 0.f}};
    const unsigned short* W3p = Welb + (w * 16 + lr) * 64 + lk8;
#pragma unroll
    for (int ks = 0; ks < 2; ++ks) {
      short8 a = *(const short8*)(W3p + ks * 32);
      int kb = ks * 64 + lk8 * 2;
      short8 b0 = *(const short8*)(xnb + lr * 128 + (kb ^ swzr));
      short8 b1 = *(const short8*)(xnb + (16 + lr) * 128 + (kb ^ swzr));
      acc3[0] = __builtin_amdgcn_mfma_f32_16x16x32_bf16(a, b0, acc3[0], 0, 0, 0);
      acc3[1] = __builtin_amdgcn_mfma_f32_16x16x32_bf16(a, b1, acc3[1], 0, 0, 0);
    }
    int o0 = w * 16 + jo;
#pragma unroll
    for (int nt = 0; nt < 2; ++nt) {
      int node = n0 + nt * 16 + lr;
      if (node < N) {
        unsigned lo = (unsigned)f2bf(acc3[nt][0]) | ((unsigned)f2bf(acc3[nt][1]) << 16);
        unsigned hi = (unsigned)f2bf(acc3[nt][2]) | ((unsigned)f2bf(acc3[nt][3]) << 16);
        *(uint2*)(y_bf + (size_t)node * 64 + o0) = make_uint2(lo, hi);
      }
    }
  } else {
    // ---- fused output projection ----
    float4 w0 = *(const float4*)(Wo0 + h0);
    float4 w1 = *(const float4*)(Wo1 + h0);
    float* ow = (float*)h1h;  // [4 waves][2 outs][32 nodes]
#pragma unroll
    for (int nt = 0; nt < 2; ++nt) {
      float p0 = xn[nt].x * w0.x + xn[nt].y * w0.y + xn[nt].z * w0.z + xn[nt].w * w0.w;
      float p1 = xn[nt].x * w1.x + xn[nt].y * w1.y + xn[nt].z * w1.z + xn[nt].w * w1.w;
      p0 += __shfl_xor(p0, 16); p0 += __shfl_xor(p0, 32);
      p1 += __shfl_xor(p1, 16); p1 += __shfl_xor(p1, 32);
      if (lane < 16) {
        ow[w * 64 + 0 + nt * 16 + lr] = p0;
        ow[w * 64 + 32 + nt * 16 + lr] = p1;
      }
    }
    __syncthreads();
    if (t < 64) {
      int oi = t >> 5, nd = t & 31;
      int node = n0 + nd;
      if (node < N) {
        float v = ow[0 * 64 + oi * 32 + nd] + ow[1 * 64 + oi * 32 + nd] +
                  ow[2 * 64 + oi * 32 + nd] + ow[3 * 64 + oi * 32 + nd];
        v += (oi ? bo1[0] : bo0[0]);
        outp[(size_t)oi * N + node] = v;
      }
    }
  }
}

// per-graph (256 threads): parallel partial-reduce + split-K GEMVs + LSTM
__global__ __launch_bounds__(256) void k_graph(const int* __restrict__ gstart,
                                               const int* __restrict__ gend,
                                               const float* __restrict__ bmaxA,
                                               const float* __restrict__ bmaxB,
                                               const int* __restrict__ bgidA,
                                               const int* __restrict__ bgidB,
                                               unsigned* __restrict__ xu_enc,
                                               float* __restrict__ u,
                                               const float* __restrict__ W_gl,
                                               const float* __restrict__ b_gl,
                                               const float* __restrict__ W_ih,
                                               const float* __restrict__ b_ih,
                                               const float* __restrict__ b_hh,
                                               float* __restrict__ c_out) {
  __shared__ float red[4][3][64];
  __shared__ float xu_s[64], us[64], un[64];
  int g = blockIdx.x;
  int t = threadIdx.x, h = t & 63, qd = t >> 6;
  const float NEG = -__builtin_huge_valf();

  // strided block-partial reduce across 4 waves
  float m = NEG;
  int gs = gstart[g], ge = gend[g];
  if (gs < ge) {
    int bs = gs >> 5, be = (ge - 1) >> 5;
    for (int b = bs + qd; b <= be; b += 4) {
      if (bgidA[b] == g) m = fmaxf(m, bmaxA[(size_t)b * 64 + h]);
      if (bgidB[b] == g) m = fmaxf(m, bmaxB[(size_t)b * 64 + h]);
    }
  }
  red[qd][0][h] = m;
  __syncthreads();
  if (qd == 0) {
    m = fmaxf(fmaxf(red[0][0][h], red[1][0][h]), fmaxf(red[2][0][h], red[3][0][h]));
    unsigned Ev = xu_enc[g * 64 + h];  // fallback decode + reset
    float fd = (Ev & 0x80000000u) ? __uint_as_float(Ev & 0x7FFFFFFFu)
                                  : __uint_as_float(~Ev);
    m = fmaxf(m, fd);
    xu_enc[g * 64 + h] = 0x007FFFFFu;
    xu_s[h] = isfinite(m) ? m : 0.f;
    us[h] = u[g * 64 + h];
  }
  __syncthreads();

  // W_gl GEMV split-K: pre[h] = b_gl[h] + [xu|us] . W_gl[h]
  float pre = 0.f;
  {
    const float* Wrow = W_gl + h * 128 + qd * 32;
    const float* src = (qd < 2) ? (xu_s + qd * 32) : (us + (qd - 2) * 32);
#pragma unroll 8
    for (int k = 0; k < 32; ++k) pre += src[k] * Wrow[k];
  }
  red[qd][0][h] = pre;
  __syncthreads();
  if (qd == 0) {
    float prs = red[0][0][h] + red[1][0][h] + red[2][0][h] + red[3][0][h] + b_gl[h];
    un[h] = us[h] + fmaxf(prs, 0.f);
  }
  __syncthreads();

  // LSTM gates split-K (16 each over 4 waves)
  float gi = 0.f, gg = 0.f, go = 0.f;
#pragma unroll 4
  for (int k = qd * 16; k < qd * 16 + 16; ++k) {
    float uv = un[k];
    gi += uv * W_ih[h * 64 + k];
    gg += uv * W_ih[(128 + h) * 64 + k];
    go += uv * W_ih[(192 + h) * 64 + k];
  }
  red[qd][0][h] = gi; red[qd][1][h] = gg; red[qd][2][h] = go;
  __syncthreads();
  if (qd == 0) {
    gi = red[0][0][h] + red[1][0][h] + red[2][0][h] + red[3][0][h] + b_ih[h] + b_hh[h];
    gg = red[0][1][h] + red[1][1][h] + red[2][1][h] + red[3][1][h] +
         b_ih[128 + h] + b_hh[128 + h];
    go = red[0][2][h] + red[1][2][h] + red[2][2][h] + red[3][2][h] +
         b_ih[192 + h] + b_hh[192 + h];
    float cc = (1.f / (1.f + expf(-gi))) * tanhf(gg);
    float u2v = (1.f / (1.f + expf(-go))) * tanhf(cc);
    c_out[g * 64 + h] = cc;
    u[g * 64 + h] = u2v;
  }
}

extern "C" void kernel_launch(void* const* d_in, const int* in_sizes, int n_in,
                              void* d_out, int out_size, void* d_ws, size_t ws_size,
                              hipStream_t stream) {
  const float* v0 = (const float*)d_in[0];
  const float* v1 = (const float*)d_in[1];
  const float* dist = (const float*)d_in[2];
  const int* eidx = (const int*)d_in[3];
  const int* batch = (const int*)d_in[4];
  const float* wte = (const float*)d_in[6];
  const float* Wi0 = (const float*)d_in[7];
  const float* bi0 = (const float*)d_in[8];
  const float* Wi1 = (const float*)d_in[9];
  const float* bi1 = (const float*)d_in[10];
  const float* Wo0 = (const float*)d_in[11];
  const float* bo0 = (const float*)d_in[12];
  const float* Wo1 = (const float*)d_in[13];
  const float* bo1 = (const float*)d_in[14];
  const float* W_edge = (const float*)d_in[15];
  const float* b_edge = (const float*)d_in[16];
  const float* W_el = (const float*)d_in[17];
  const float* b_el = (const float*)d_in[18];
  const float* W_n1 = (const float*)d_in[19];
  const float* b_n1 = (const float*)d_in[20];
  const float* W_n2 = (const float*)d_in[21];
  const float* b_n2 = (const float*)d_in[22];
  const float* W_gl = (const float*)d_in[23];
  const float* b_gl = (const float*)d_in[24];
  const float* W_ih = (const float*)d_in[25];
  const float* b_ih = (const float*)d_in[27];
  const float* b_hh = (const float*)d_in[28];

  const int N = in_sizes[0];
  const int E = in_sizes[2];
  const int NH = N * 64;
  const int NB512 = (N + 511) / 512;
  const int nblk = (N + 31) / 32;

  float* ws = (float*)d_ws;
  float* x = ws;                                   // NH
  float* u = x + NH;                               // 4096
  unsigned* xu_enc = (unsigned*)(u + 4096);        // 4096
  float* p = (float*)(xu_enc + 4096);
  float* q = p + 64;
  float* c0 = q + 64;
  float* c1 = c0 + 64;
  float* c2 = c1 + 64;
  unsigned short* W1b = (unsigned short*)(c2 + 64);  // 49152
  unsigned short* W2b = W1b + 49152;                 // 16384
  unsigned short* Welb = W2b + 16384;                // 4096
  unsigned short* y_bf = Welb + 4096;                // NH
  int* deg = (int*)(y_bf + NH);                      // N
  int* off = deg + N;                                // N
  int* cur = off + N;                                // N
  int* bsum = cur + N;                               // 128
  int* gstart = bsum + 128;                          // 64
  int* gend = gstart + 64;                           // 64
  int* bgidA = gend + 64;                            // nblk
  int* bgidB = bgidA + nblk;                         // nblk
  float* bmaxA = (float*)(bgidB + nblk);             // nblk*64
  float* bmaxB = bmaxA + (size_t)nblk * 64;          // nblk*64
  uint2* spack = (uint2*)(((size_t)(bmaxB + (size_t)nblk * 64) + 15) & ~(size_t)15);  // E

  float* outp = (float*)d_out;

  k_init<<<(77824 + 3 * N + 64 + 255) / 256, 256, 0, stream>>>(
      v0, v1, wte, Wi0, bi0, Wi1, bi1, batch, gstart, gend,
      u, xu_enc, W1b, W2b, Welb, W_n1, W_n2, W_el, b_el, W_edge, b_edge,
      p, q, c0, c1, c2, deg, cur, N);
  k_hist<<<(E + 255) / 256, 256, 0, stream>>>(eidx, deg, E);
  k_scan1<<<NB512, 256, 0, stream>>>(deg, off, bsum, N);
  k_scan2<<<1, 128, 0, stream>>>(bsum, NB512);
  k_scatter<<<(E + 255) / 256, 256, 0, stream>>>(eidx, dist, off, bsum, cur, spack, E);

  for (int l = 0; l < 4; ++l) {
    if (l == 0) {
      k_node<0><<<nblk, 256, 0, stream>>>(off, bsum, spack, p, q, c0, c1, c2, v0, v1,
                                          wte, Wi0, bi0, Wi1, bi1,
                                          x, y_bf, batch, u, W1b, W2b, Welb, b_n1, b_n2,
                                          xu_enc, bmaxA, bmaxB, bgidA, bgidB,
                                          Wo0, bo0, Wo1, bo1, outp, N);
    } else if (l < 3) {
      k_node<1><<<nblk, 256, 0, stream>>>(off, bsum, spack, p, q, c0, c1, c2, v0, v1,
                                          wte, Wi0, bi0, Wi1, bi1,
                                          x, y_bf, batch, u, W1b, W2b, Welb, b_n1, b_n2,
                                          xu_enc, bmaxA, bmaxB, bgidA, bgidB,
                                          Wo0, bo0, Wo1, bo1, outp, N);
    } else {
      k_node<2><<<nblk, 256, 0, stream>>>(off, bsum, spack, p, q, c0, c1, c2, v0, v1,
                                          wte, Wi0, bi0, Wi1, bi1,
                                          x, y_bf, batch, u, W1b, W2b, Welb, b_n1, b_n2,
                                          xu_enc, bmaxA, bmaxB, bgidA, bgidB,
                                          Wo0, bo0, Wo1, bo1, outp, N);
    }
    k_graph<<<64, 256, 0, stream>>>(gstart, gend, bmaxA, bmaxB, bgidA, bgidB,
                                    xu_enc, u, W_gl, b_gl, W_ih, b_ih, b_hh,
                                    outp + 2 * N + l * 4096);
  }
}